// Round 1
// baseline (6148.209 us; speedup 1.0000x reference)
//
#include <hip/hip_runtime.h>
#include <math.h>

#define N_NODES 100000
#define N_EDGES 1600000
#define NGR 64
#define IMG_F 50176
#define NCLS 38

// ---------------- small helpers ----------------
__device__ __forceinline__ int lower_bound_i(const int* __restrict__ a, int n, int v) {
  int lo = 0, hi = n;
  while (lo < hi) { int mid = (lo + hi) >> 1; if (a[mid] < v) lo = mid + 1; else hi = mid; }
  return lo;
}

__global__ void k_deg(const int* __restrict__ dst, int* __restrict__ deg) {
  int e = blockIdx.x * 256 + threadIdx.x;
  if (e < N_EDGES) atomicAdd(&deg[dst[e]], 1);
}

__global__ void k_dinv(const int* __restrict__ deg, float* __restrict__ dinv) {
  int n = blockIdx.x * 256 + threadIdx.x;
  if (n < N_NODES) dinv[n] = rsqrtf((float)deg[n] + 1.0f);  // deg = indeg, +1 self-loop
}

__global__ void k_coeff(const int* __restrict__ src, const int* __restrict__ dst,
                        const float* __restrict__ dinv, float* __restrict__ coeff) {
  int e = blockIdx.x * 256 + threadIdx.x;
  if (e < N_EDGES) coeff[e] = dinv[src[e]] * dinv[dst[e]];
}

// ---------------- node GEMM: C[M,N] = act(A[M,K]) @ W[K,N] ----------------
// Block tile 128 rows x BN cols, thread tile 8x8, K-chunk 64.
// LDS XOR-swizzled at float4 granularity: staging stores <=2-way (free),
// inner ds_read_b128 conflict-free.
template<int K, int N, int BN, bool RELU_BIAS>
__global__ __launch_bounds__(16*(BN/8))
void k_gemm_node(const float* __restrict__ A, const float* __restrict__ W,
                 const float* __restrict__ abias, float* __restrict__ C, int M) {
  constexpr int BM = 128, KB = 64;
  constexpr int NT = 16 * (BN / 8);
  __shared__ float As[KB * BM];   // As[c][swizzled r], c = k within chunk
  __shared__ float Ws[KB * BN];
  const int tid = threadIdx.x;
  const int rg = tid / (BN / 8);  // row group 0..15
  const int cg = tid % (BN / 8);  // col group
  const int row0 = blockIdx.x * BM;
  float acc[8][8];
#pragma unroll
  for (int i = 0; i < 8; i++)
#pragma unroll
    for (int j = 0; j < 8; j++) acc[i][j] = 0.f;

  for (int k0 = 0; k0 < K; k0 += KB) {
#pragma unroll
    for (int i = tid; i < BM * (KB/4); i += NT) {
      int r = i / (KB / 4);
      int kq = i % (KB / 4);
      int row = row0 + r;
      float4 v = make_float4(0.f, 0.f, 0.f, 0.f);
      if (row < M) {
        v = *(const float4*)&A[(size_t)row * K + k0 + kq * 4];
        if (RELU_BIAS) {
          v.x = fmaxf(v.x + abias[k0 + kq*4 + 0], 0.f);
          v.y = fmaxf(v.y + abias[k0 + kq*4 + 1], 0.f);
          v.z = fmaxf(v.z + abias[k0 + kq*4 + 2], 0.f);
          v.w = fmaxf(v.w + abias[k0 + kq*4 + 3], 0.f);
        }
      }
      int r4 = r >> 2, rm = r & 3;
      { int c = kq*4+0; As[c*BM + ((r4 ^ (c & 31)) << 2) + rm] = v.x; }
      { int c = kq*4+1; As[c*BM + ((r4 ^ (c & 31)) << 2) + rm] = v.y; }
      { int c = kq*4+2; As[c*BM + ((r4 ^ (c & 31)) << 2) + rm] = v.z; }
      { int c = kq*4+3; As[c*BM + ((r4 ^ (c & 31)) << 2) + rm] = v.w; }
    }
#pragma unroll
    for (int i = tid; i < KB * (BN/4); i += NT) {
      int kk = i / (BN / 4);
      int cq = i % (BN / 4);
      float4 v = *(const float4*)&W[(size_t)(k0 + kk) * N + cq * 4];
      *(float4*)&Ws[kk*BN + ((cq ^ (kk & (BN/4 - 1))) << 2)] = v;
    }
    __syncthreads();
#pragma unroll
    for (int kk = 0; kk < KB; kk++) {
      float a[8], b[8];
      *(float4*)&a[0] = *(const float4*)&As[kk*BM + ((((rg<<1)+0) ^ (kk & 31)) << 2)];
      *(float4*)&a[4] = *(const float4*)&As[kk*BM + ((((rg<<1)+1) ^ (kk & 31)) << 2)];
      *(float4*)&b[0] = *(const float4*)&Ws[kk*BN + ((((cg<<1)+0) ^ (kk & (BN/4-1))) << 2)];
      *(float4*)&b[4] = *(const float4*)&Ws[kk*BN + ((((cg<<1)+1) ^ (kk & (BN/4-1))) << 2)];
#pragma unroll
      for (int i = 0; i < 8; i++)
#pragma unroll
        for (int j = 0; j < 8; j++)
          acc[i][j] = fmaf(a[i], b[j], acc[i][j]);
    }
    __syncthreads();
  }
#pragma unroll
  for (int i = 0; i < 8; i++) {
    int row = row0 + rg*8 + i;
    if (row < M) {
      float4 v0 = make_float4(acc[i][0], acc[i][1], acc[i][2], acc[i][3]);
      float4 v1 = make_float4(acc[i][4], acc[i][5], acc[i][6], acc[i][7]);
      *(float4*)&C[(size_t)row * N + cg*8 + 0] = v0;
      *(float4*)&C[(size_t)row * N + cg*8 + 4] = v1;
    }
  }
}

// ---------------- img GEMM (split-K, atomic accumulate) ----------------
// C[64,1024] += A[64,50176-chunk] @ B[chunk,1024]; C pre-initialized with bias.
__global__ __launch_bounds__(256)
void k_img_gemm(const float* __restrict__ A, const float* __restrict__ B,
                float* __restrict__ C) {
  constexpr int KB = 32;
  __shared__ float As[KB * 64];
  __shared__ float Bs[KB * 256];
  const int tid = threadIdx.x;
  const int cg = tid % 32;
  const int rg = tid / 32;
  const int col0 = blockIdx.x * 256;
  const int kc0 = blockIdx.y * 256;
  float acc[8][8];
#pragma unroll
  for (int i = 0; i < 8; i++)
#pragma unroll
    for (int j = 0; j < 8; j++) acc[i][j] = 0.f;

  for (int s = 0; s < 256; s += KB) {
    int kb = kc0 + s;
#pragma unroll
    for (int i = tid; i < 64 * (KB/4); i += 256) {
      int r = i / (KB / 4);
      int kq = i % (KB / 4);
      float4 v = *(const float4*)&A[(size_t)r * IMG_F + kb + kq * 4];
      int r4 = r >> 2, rm = r & 3;
      { int c = kq*4+0; As[c*64 + ((r4 ^ (c & 15)) << 2) + rm] = v.x; }
      { int c = kq*4+1; As[c*64 + ((r4 ^ (c & 15)) << 2) + rm] = v.y; }
      { int c = kq*4+2; As[c*64 + ((r4 ^ (c & 15)) << 2) + rm] = v.z; }
      { int c = kq*4+3; As[c*64 + ((r4 ^ (c & 15)) << 2) + rm] = v.w; }
    }
#pragma unroll
    for (int i = tid; i < KB * 64; i += 256) {
      int kk = i / 64;
      int cq = i % 64;
      float4 v = *(const float4*)&B[(size_t)(kb + kk) * 1024 + col0 + cq * 4];
      *(float4*)&Bs[kk*256 + ((cq ^ (kk & 63)) << 2)] = v;
    }
    __syncthreads();
#pragma unroll
    for (int kk = 0; kk < KB; kk++) {
      float a[8], b[8];
      *(float4*)&a[0] = *(const float4*)&As[kk*64  + ((((rg<<1)+0) ^ (kk & 15)) << 2)];
      *(float4*)&a[4] = *(const float4*)&As[kk*64  + ((((rg<<1)+1) ^ (kk & 15)) << 2)];
      *(float4*)&b[0] = *(const float4*)&Bs[kk*256 + ((((cg<<1)+0) ^ (kk & 63)) << 2)];
      *(float4*)&b[4] = *(const float4*)&Bs[kk*256 + ((((cg<<1)+1) ^ (kk & 63)) << 2)];
#pragma unroll
      for (int i = 0; i < 8; i++)
#pragma unroll
        for (int j = 0; j < 8; j++)
          acc[i][j] = fmaf(a[i], b[j], acc[i][j]);
    }
    __syncthreads();
  }
#pragma unroll
  for (int i = 0; i < 8; i++)
#pragma unroll
    for (int j = 0; j < 8; j++)
      atomicAdd(&C[(rg*8 + i) * 1024 + col0 + cg*8 + j], acc[i][j]);
}

__global__ void k_tmp1_init(const float* __restrict__ bm0, float* __restrict__ t) {
  int i = blockIdx.x * 256 + threadIdx.x;
  if (i < 64 * 1024) t[i] = bm0[i & 1023];
}

// x0[64,64] = tmp1[64,1024] @ Wm1[1024,64] + bm1
__global__ __launch_bounds__(256)
void k_img_gemm2(const float* __restrict__ T, const float* __restrict__ Wm1,
                 const float* __restrict__ bm1, float* __restrict__ x0) {
  int r = blockIdx.x;
  int c = threadIdx.x & 63;
  int q = threadIdx.x >> 6;
  float acc = 0.f;
#pragma unroll 8
  for (int k = q; k < 1024; k += 4)
    acc = fmaf(T[r*1024 + k], Wm1[k*64 + c], acc);
  __shared__ float red[4][64];
  red[q][c] = acc;
  __syncthreads();
  if (q == 0) x0[r*64 + c] = red[0][c] + red[1][c] + red[2][c] + red[3][c] + bm1[c];
}

// ---------------- GCN aggregation ----------------
// out[n] = h[n]*dinv[n]^2  (self-loop), then edge atomics add h[s]*dinv[s]*dinv[d].
template<int F>
__global__ void k_agg_init(const float* __restrict__ h, const float* __restrict__ dinv,
                           float* __restrict__ out) {
  constexpr int Q = F / 4;
  int i = blockIdx.x * 256 + threadIdx.x;          // float4 index
  if (i >= N_NODES * Q) return;
  int n = i / Q;
  float sc = dinv[n]; sc *= sc;
  float4 v = *(const float4*)&h[(size_t)i * 4];
  float4 o = make_float4(v.x*sc, v.y*sc, v.z*sc, v.w*sc);
  *(float4*)&out[(size_t)i * 4] = o;
}

template<int F>
__global__ void k_agg_edge(const float* __restrict__ h, const float* __restrict__ coeff,
                           const int* __restrict__ src, const int* __restrict__ dst,
                           float* __restrict__ out) {
  constexpr int Q = F / 4;
  int t = blockIdx.x * 256 + threadIdx.x;          // exact multiple of 256
  int e = t / Q;
  int q = t % Q;
  float c = coeff[e];
  int s = src[e], d = dst[e];
  float4 v = *(const float4*)&h[(size_t)s * F + q * 4];
  float* o = &out[(size_t)d * F + q * 4];
  atomicAdd(o + 0, v.x * c);
  atomicAdd(o + 1, v.y * c);
  atomicAdd(o + 2, v.z * c);
  atomicAdd(o + 3, v.w * c);
}

// ---------------- pool: g[b] = sum_n relu(h2raw[n]+b2), batch sorted ----------------
__global__ __launch_bounds__(256)
void k_pool(const float* __restrict__ h2, const float* __restrict__ b2,
            const int* __restrict__ batch, float* __restrict__ g) {
  int b = blockIdx.x;
  int f = threadIdx.x & 63;
  int q = threadIdx.x >> 6;
  int lo = lower_bound_i(batch, N_NODES, b);
  int hi = lower_bound_i(batch, N_NODES, b + 1);
  float bias = b2[f];
  float acc = 0.f;
  for (int i = lo + q; i < hi; i += 4)
    acc += fmaxf(h2[(size_t)i * 64 + f] + bias, 0.f);
  __shared__ float red[4][64];
  red[q][f] = acc;
  __syncthreads();
  if (q == 0) g[b*64 + f] = red[0][f] + red[1][f] + red[2][f] + red[3][f];
}

// ---------------- head: gm=g@Wmx+bmx; logits=[x0,gm]@Wfc+bfc; log_softmax ----------------
__global__ __launch_bounds__(64)
void k_final(const float* __restrict__ x0, const float* __restrict__ g,
             const float* __restrict__ Wmx, const float* __restrict__ bmx,
             const float* __restrict__ Wfc, const float* __restrict__ bfc,
             float* __restrict__ out) {
  int r = blockIdx.x;
  int c = threadIdx.x;  // 0..63
  __shared__ float sx[128];
  __shared__ float slog[NCLS];
  __shared__ float sred;
  float acc = bmx[c];
#pragma unroll 8
  for (int k = 0; k < 64; k++) acc = fmaf(g[r*64 + k], Wmx[k*64 + c], acc);
  sx[64 + c] = acc;
  sx[c] = x0[r*64 + c];
  __syncthreads();
  float lg = 0.f;
  if (c < NCLS) {
    lg = bfc[c];
#pragma unroll 8
    for (int k = 0; k < 128; k++) lg = fmaf(sx[k], Wfc[k*NCLS + c], lg);
    slog[c] = lg;
  }
  __syncthreads();
  if (c == 0) {
    float m = -1e30f;
    for (int j = 0; j < NCLS; j++) m = fmaxf(m, slog[j]);
    float s = 0.f;
    for (int j = 0; j < NCLS; j++) s += expf(slog[j] - m);
    sred = m + logf(s);
  }
  __syncthreads();
  if (c < NCLS) out[r*NCLS + c] = lg - sred;
}

// ---------------- launch ----------------
extern "C" void kernel_launch(void* const* d_in, const int* in_sizes, int n_in,
                              void* d_out, int out_size, void* d_ws, size_t ws_size,
                              hipStream_t stream) {
  const float* x    = (const float*)d_in[0];
  const int*   edge = (const int*)d_in[1];
  const float* img  = (const float*)d_in[2];
  const int*   batch= (const int*)d_in[3];
  const float* W1   = (const float*)d_in[4];
  const float* b1   = (const float*)d_in[5];
  const float* W2   = (const float*)d_in[6];
  const float* b2   = (const float*)d_in[7];
  const float* Wm0  = (const float*)d_in[8];
  const float* bm0  = (const float*)d_in[9];
  const float* Wm1  = (const float*)d_in[10];
  const float* bm1  = (const float*)d_in[11];
  const float* Wmx  = (const float*)d_in[12];
  const float* bmx  = (const float*)d_in[13];
  const float* Wfc  = (const float*)d_in[14];
  const float* bfc  = (const float*)d_in[15];
  float* out = (float*)d_out;
  const int* srcp = edge;
  const int* dstp = edge + N_EDGES;

  // workspace carve-up (~111 MB total)
  char* ws = (char*)d_ws;
  size_t off = 0;
  auto alloc = [&](size_t bytes) {
    void* p = ws + off;
    off += (bytes + 255) & ~(size_t)255;
    return p;
  };
  int*   deg   = (int*)  alloc((size_t)N_NODES * 4);
  float* dinv  = (float*)alloc((size_t)N_NODES * 4);
  float* coeff = (float*)alloc((size_t)N_EDGES * 4);
  float* bufA  = (float*)alloc((size_t)N_NODES * 128 * 4);  // h1_lin, later h2_lin
  float* bufB  = (float*)alloc((size_t)N_NODES * 128 * 4);  // h1 raw agg, later h2 raw agg
  float* tmp1  = (float*)alloc(64 * 1024 * 4);
  float* x0    = (float*)alloc(64 * 64 * 4);
  float* g     = (float*)alloc(64 * 64 * 4);
  (void)ws_size; (void)in_sizes; (void)n_in; (void)out_size;

  // degrees -> dinv -> per-edge coeff
  hipMemsetAsync(deg, 0, (size_t)N_NODES * 4, stream);
  k_deg  <<<(N_EDGES + 255) / 256, 256, 0, stream>>>(dstp, deg);
  k_dinv <<<(N_NODES + 255) / 256, 256, 0, stream>>>(deg, dinv);
  k_coeff<<<(N_EDGES + 255) / 256, 256, 0, stream>>>(srcp, dstp, dinv, coeff);

  // image branch
  k_tmp1_init<<<(64 * 1024) / 256, 256, 0, stream>>>(bm0, tmp1);
  k_img_gemm <<<dim3(4, 196), 256, 0, stream>>>(img, Wm0, tmp1);
  k_img_gemm2<<<64, 256, 0, stream>>>(tmp1, Wm1, bm1, x0);

  // GCN layer 1: h1_lin = x @ W1 ; agg ; (bias+relu fused into GEMM2's A-load)
  k_gemm_node<128, 128, 128, false><<<(N_NODES + 127) / 128, 256, 0, stream>>>(
      x, W1, nullptr, bufA, N_NODES);
  k_agg_init<128><<<(N_NODES * 32) / 256, 256, 0, stream>>>(bufA, dinv, bufB);
  k_agg_edge<128><<<(N_EDGES * 32) / 256, 256, 0, stream>>>(bufA, coeff, srcp, dstp, bufB);

  // GCN layer 2: h2_lin = relu(h1raw + b1) @ W2 ; agg ; (bias+relu fused into pool)
  k_gemm_node<128, 64, 64, true><<<(N_NODES + 127) / 128, 128, 0, stream>>>(
      bufB, W2, b1, bufA, N_NODES);
  k_agg_init<64><<<(N_NODES * 16) / 256, 256, 0, stream>>>(bufA, dinv, bufB);
  k_agg_edge<64><<<(N_EDGES * 16) / 256, 256, 0, stream>>>(bufA, coeff, srcp, dstp, bufB);

  // pool + head
  k_pool <<<NGR, 256, 0, stream>>>(bufB, b2, batch, g);
  k_final<<<NGR, 64, 0, stream>>>(x0, g, Wmx, bmx, Wfc, bfc, out);
}

// Round 2
// 2275.510 us; speedup vs baseline: 2.7019x; 2.7019x over previous
//
#include <hip/hip_runtime.h>
#include <math.h>

#define N_NODES 100000
#define N_EDGES 1600000
#define NGR 64
#define IMG_F 50176
#define NCLS 38

// ---------------- small helpers ----------------
__device__ __forceinline__ int lower_bound_i(const int* __restrict__ a, int n, int v) {
  int lo = 0, hi = n;
  while (lo < hi) { int mid = (lo + hi) >> 1; if (a[mid] < v) lo = mid + 1; else hi = mid; }
  return lo;
}

__global__ void k_deg(const int* __restrict__ dst, int* __restrict__ deg) {
  int e = blockIdx.x * 256 + threadIdx.x;
  if (e < N_EDGES) atomicAdd(&deg[dst[e]], 1);
}

__global__ void k_dinv(const int* __restrict__ deg, float* __restrict__ dinv) {
  int n = blockIdx.x * 256 + threadIdx.x;
  if (n < N_NODES) dinv[n] = rsqrtf((float)deg[n] + 1.0f);  // deg = indeg, +1 self-loop
}

// ---------------- block scan: rowptr = exclusive_scan(deg) ----------------
// Phase 1: per-block (512 elems) sums. Phase 2: scan of 196 block sums.
// Phase 3: per-block LDS scan + offset -> rowptr.
#define SCAN_CHUNK 512
#define SCAN_BLOCKS ((N_NODES + SCAN_CHUNK - 1) / SCAN_CHUNK)  // 196

__global__ __launch_bounds__(512)
void k_scan1(const int* __restrict__ deg, int* __restrict__ bsum) {
  __shared__ int s[512];
  int t = threadIdx.x;
  int i = blockIdx.x * SCAN_CHUNK + t;
  s[t] = (i < N_NODES) ? deg[i] : 0;
  __syncthreads();
  for (int off = 256; off > 0; off >>= 1) {
    if (t < off) s[t] += s[t + off];
    __syncthreads();
  }
  if (t == 0) bsum[blockIdx.x] = s[0];
}

__global__ __launch_bounds__(256)
void k_scan2(const int* __restrict__ bsum, int* __restrict__ boff) {
  __shared__ int s[256];
  int t = threadIdx.x;
  s[t] = (t < SCAN_BLOCKS) ? bsum[t] : 0;
  __syncthreads();
  for (int off = 1; off < 256; off <<= 1) {
    int v = (t >= off) ? s[t - off] : 0;
    __syncthreads();
    s[t] += v;
    __syncthreads();
  }
  if (t < SCAN_BLOCKS) boff[t] = (t == 0) ? 0 : s[t - 1];
}

__global__ __launch_bounds__(512)
void k_scan3(const int* __restrict__ deg, const int* __restrict__ boff,
             int* __restrict__ rowptr) {
  __shared__ int s[512];
  int t = threadIdx.x;
  int i = blockIdx.x * SCAN_CHUNK + t;
  int d = (i < N_NODES) ? deg[i] : 0;
  s[t] = d;
  __syncthreads();
  for (int off = 1; off < 512; off <<= 1) {
    int v = (t >= off) ? s[t - off] : 0;
    __syncthreads();
    s[t] += v;
    __syncthreads();
  }
  if (i < N_NODES) rowptr[i] = boff[blockIdx.x] + s[t] - d;  // exclusive
  if (blockIdx.x == 0 && t == 0) rowptr[N_NODES] = N_EDGES;
}

// scatter edges into CSR order (grouped by dst); cur must be zeroed
__global__ void k_csr_fill(const int* __restrict__ src, const int* __restrict__ dst,
                           const int* __restrict__ rowptr, int* __restrict__ cur,
                           int* __restrict__ csr_src) {
  int e = blockIdx.x * 256 + threadIdx.x;
  if (e >= N_EDGES) return;
  int d = dst[e];
  int pos = rowptr[d] + atomicAdd(&cur[d], 1);
  csr_src[pos] = src[e];
}

// ---------------- GCN aggregation (gather, atomic-free) ----------------
// out[n] = dinv[n]^2 * h[n] + sum_{e: dst=n} dinv[src]*dinv[n] * h[src]
template<int F>
__global__ __launch_bounds__(256)
void k_agg_gather(const float* __restrict__ h, const float* __restrict__ dinv,
                  const int* __restrict__ rowptr, const int* __restrict__ csr_src,
                  float* __restrict__ out) {
  constexpr int L = F / 4;            // lanes per node
  constexpr int NPB = 256 / L;        // nodes per block
  int n = blockIdx.x * NPB + threadIdx.x / L;
  int lane = threadIdx.x % L;
  if (n >= N_NODES) return;
  float dn = dinv[n];
  float4 v = *(const float4*)&h[(size_t)n * F + lane * 4];
  float sc = dn * dn;
  float4 acc = make_float4(v.x * sc, v.y * sc, v.z * sc, v.w * sc);
  int lo = rowptr[n], hi = rowptr[n + 1];
  for (int i = lo; i < hi; i++) {
    int s = csr_src[i];
    float c = dinv[s] * dn;
    float4 u = *(const float4*)&h[(size_t)s * F + lane * 4];
    acc.x = fmaf(u.x, c, acc.x);
    acc.y = fmaf(u.y, c, acc.y);
    acc.z = fmaf(u.z, c, acc.z);
    acc.w = fmaf(u.w, c, acc.w);
  }
  *(float4*)&out[(size_t)n * F + lane * 4] = acc;
}

// ---------------- node GEMM: C[M,N] = act(A[M,K]) @ W[K,N] ----------------
template<int K, int N, int BN, bool RELU_BIAS>
__global__ __launch_bounds__(16*(BN/8))
void k_gemm_node(const float* __restrict__ A, const float* __restrict__ W,
                 const float* __restrict__ abias, float* __restrict__ C, int M) {
  constexpr int BM = 128, KB = 64;
  constexpr int NT = 16 * (BN / 8);
  __shared__ float As[KB * BM];
  __shared__ float Ws[KB * BN];
  const int tid = threadIdx.x;
  const int rg = tid / (BN / 8);
  const int cg = tid % (BN / 8);
  const int row0 = blockIdx.x * BM;
  float acc[8][8];
#pragma unroll
  for (int i = 0; i < 8; i++)
#pragma unroll
    for (int j = 0; j < 8; j++) acc[i][j] = 0.f;

  for (int k0 = 0; k0 < K; k0 += KB) {
#pragma unroll
    for (int i = tid; i < BM * (KB/4); i += NT) {
      int r = i / (KB / 4);
      int kq = i % (KB / 4);
      int row = row0 + r;
      float4 v = make_float4(0.f, 0.f, 0.f, 0.f);
      if (row < M) {
        v = *(const float4*)&A[(size_t)row * K + k0 + kq * 4];
        if (RELU_BIAS) {
          v.x = fmaxf(v.x + abias[k0 + kq*4 + 0], 0.f);
          v.y = fmaxf(v.y + abias[k0 + kq*4 + 1], 0.f);
          v.z = fmaxf(v.z + abias[k0 + kq*4 + 2], 0.f);
          v.w = fmaxf(v.w + abias[k0 + kq*4 + 3], 0.f);
        }
      }
      int r4 = r >> 2, rm = r & 3;
      { int c = kq*4+0; As[c*BM + ((r4 ^ (c & 31)) << 2) + rm] = v.x; }
      { int c = kq*4+1; As[c*BM + ((r4 ^ (c & 31)) << 2) + rm] = v.y; }
      { int c = kq*4+2; As[c*BM + ((r4 ^ (c & 31)) << 2) + rm] = v.z; }
      { int c = kq*4+3; As[c*BM + ((r4 ^ (c & 31)) << 2) + rm] = v.w; }
    }
#pragma unroll
    for (int i = tid; i < KB * (BN/4); i += NT) {
      int kk = i / (BN / 4);
      int cq = i % (BN / 4);
      float4 v = *(const float4*)&W[(size_t)(k0 + kk) * N + cq * 4];
      *(float4*)&Ws[kk*BN + ((cq ^ (kk & (BN/4 - 1))) << 2)] = v;
    }
    __syncthreads();
#pragma unroll
    for (int kk = 0; kk < KB; kk++) {
      float a[8], b[8];
      *(float4*)&a[0] = *(const float4*)&As[kk*BM + ((((rg<<1)+0) ^ (kk & 31)) << 2)];
      *(float4*)&a[4] = *(const float4*)&As[kk*BM + ((((rg<<1)+1) ^ (kk & 31)) << 2)];
      *(float4*)&b[0] = *(const float4*)&Ws[kk*BN + ((((cg<<1)+0) ^ (kk & (BN/4-1))) << 2)];
      *(float4*)&b[4] = *(const float4*)&Ws[kk*BN + ((((cg<<1)+1) ^ (kk & (BN/4-1))) << 2)];
#pragma unroll
      for (int i = 0; i < 8; i++)
#pragma unroll
        for (int j = 0; j < 8; j++)
          acc[i][j] = fmaf(a[i], b[j], acc[i][j]);
    }
    __syncthreads();
  }
#pragma unroll
  for (int i = 0; i < 8; i++) {
    int row = row0 + rg*8 + i;
    if (row < M) {
      float4 v0 = make_float4(acc[i][0], acc[i][1], acc[i][2], acc[i][3]);
      float4 v1 = make_float4(acc[i][4], acc[i][5], acc[i][6], acc[i][7]);
      *(float4*)&C[(size_t)row * N + cg*8 + 0] = v0;
      *(float4*)&C[(size_t)row * N + cg*8 + 4] = v1;
    }
  }
}

// ---------------- img GEMM (split-K, atomic accumulate) ----------------
__global__ __launch_bounds__(256)
void k_img_gemm(const float* __restrict__ A, const float* __restrict__ B,
                float* __restrict__ C) {
  constexpr int KB = 32;
  __shared__ float As[KB * 64];
  __shared__ float Bs[KB * 256];
  const int tid = threadIdx.x;
  const int cg = tid % 32;
  const int rg = tid / 32;
  const int col0 = blockIdx.x * 256;
  const int kc0 = blockIdx.y * 256;
  float acc[8][8];
#pragma unroll
  for (int i = 0; i < 8; i++)
#pragma unroll
    for (int j = 0; j < 8; j++) acc[i][j] = 0.f;

  for (int s = 0; s < 256; s += KB) {
    int kb = kc0 + s;
#pragma unroll
    for (int i = tid; i < 64 * (KB/4); i += 256) {
      int r = i / (KB / 4);
      int kq = i % (KB / 4);
      float4 v = *(const float4*)&A[(size_t)r * IMG_F + kb + kq * 4];
      int r4 = r >> 2, rm = r & 3;
      { int c = kq*4+0; As[c*64 + ((r4 ^ (c & 15)) << 2) + rm] = v.x; }
      { int c = kq*4+1; As[c*64 + ((r4 ^ (c & 15)) << 2) + rm] = v.y; }
      { int c = kq*4+2; As[c*64 + ((r4 ^ (c & 15)) << 2) + rm] = v.z; }
      { int c = kq*4+3; As[c*64 + ((r4 ^ (c & 15)) << 2) + rm] = v.w; }
    }
#pragma unroll
    for (int i = tid; i < KB * 64; i += 256) {
      int kk = i / 64;
      int cq = i % 64;
      float4 v = *(const float4*)&B[(size_t)(kb + kk) * 1024 + col0 + cq * 4];
      *(float4*)&Bs[kk*256 + ((cq ^ (kk & 63)) << 2)] = v;
    }
    __syncthreads();
#pragma unroll
    for (int kk = 0; kk < KB; kk++) {
      float a[8], b[8];
      *(float4*)&a[0] = *(const float4*)&As[kk*64  + ((((rg<<1)+0) ^ (kk & 15)) << 2)];
      *(float4*)&a[4] = *(const float4*)&As[kk*64  + ((((rg<<1)+1) ^ (kk & 15)) << 2)];
      *(float4*)&b[0] = *(const float4*)&Bs[kk*256 + ((((cg<<1)+0) ^ (kk & 63)) << 2)];
      *(float4*)&b[4] = *(const float4*)&Bs[kk*256 + ((((cg<<1)+1) ^ (kk & 63)) << 2)];
#pragma unroll
      for (int i = 0; i < 8; i++)
#pragma unroll
        for (int j = 0; j < 8; j++)
          acc[i][j] = fmaf(a[i], b[j], acc[i][j]);
    }
    __syncthreads();
  }
#pragma unroll
  for (int i = 0; i < 8; i++)
#pragma unroll
    for (int j = 0; j < 8; j++)
      atomicAdd(&C[(rg*8 + i) * 1024 + col0 + cg*8 + j], acc[i][j]);
}

__global__ void k_tmp1_init(const float* __restrict__ bm0, float* __restrict__ t) {
  int i = blockIdx.x * 256 + threadIdx.x;
  if (i < 64 * 1024) t[i] = bm0[i & 1023];
}

// x0[64,64] = tmp1[64,1024] @ Wm1[1024,64] + bm1
__global__ __launch_bounds__(256)
void k_img_gemm2(const float* __restrict__ T, const float* __restrict__ Wm1,
                 const float* __restrict__ bm1, float* __restrict__ x0) {
  int r = blockIdx.x;
  int c = threadIdx.x & 63;
  int q = threadIdx.x >> 6;
  float acc = 0.f;
#pragma unroll 8
  for (int k = q; k < 1024; k += 4)
    acc = fmaf(T[r*1024 + k], Wm1[k*64 + c], acc);
  __shared__ float red[4][64];
  red[q][c] = acc;
  __syncthreads();
  if (q == 0) x0[r*64 + c] = red[0][c] + red[1][c] + red[2][c] + red[3][c] + bm1[c];
}

// ---------------- pool: g[b] = sum_n relu(h2raw[n]+b2), batch sorted ----------------
__global__ __launch_bounds__(256)
void k_pool(const float* __restrict__ h2, const float* __restrict__ b2,
            const int* __restrict__ batch, float* __restrict__ g) {
  int b = blockIdx.x;
  int f = threadIdx.x & 63;
  int q = threadIdx.x >> 6;
  int lo = lower_bound_i(batch, N_NODES, b);
  int hi = lower_bound_i(batch, N_NODES, b + 1);
  float bias = b2[f];
  float acc = 0.f;
  for (int i = lo + q; i < hi; i += 4)
    acc += fmaxf(h2[(size_t)i * 64 + f] + bias, 0.f);
  __shared__ float red[4][64];
  red[q][f] = acc;
  __syncthreads();
  if (q == 0) g[b*64 + f] = red[0][f] + red[1][f] + red[2][f] + red[3][f];
}

// ---------------- head ----------------
__global__ __launch_bounds__(64)
void k_final(const float* __restrict__ x0, const float* __restrict__ g,
             const float* __restrict__ Wmx, const float* __restrict__ bmx,
             const float* __restrict__ Wfc, const float* __restrict__ bfc,
             float* __restrict__ out) {
  int r = blockIdx.x;
  int c = threadIdx.x;  // 0..63
  __shared__ float sx[128];
  __shared__ float slog[NCLS];
  __shared__ float sred;
  float acc = bmx[c];
#pragma unroll 8
  for (int k = 0; k < 64; k++) acc = fmaf(g[r*64 + k], Wmx[k*64 + c], acc);
  sx[64 + c] = acc;
  sx[c] = x0[r*64 + c];
  __syncthreads();
  float lg = 0.f;
  if (c < NCLS) {
    lg = bfc[c];
#pragma unroll 8
    for (int k = 0; k < 128; k++) lg = fmaf(sx[k], Wfc[k*NCLS + c], lg);
    slog[c] = lg;
  }
  __syncthreads();
  if (c == 0) {
    float m = -1e30f;
    for (int j = 0; j < NCLS; j++) m = fmaxf(m, slog[j]);
    float s = 0.f;
    for (int j = 0; j < NCLS; j++) s += expf(slog[j] - m);
    sred = m + logf(s);
  }
  __syncthreads();
  if (c < NCLS) out[r*NCLS + c] = lg - sred;
}

// ---------------- launch ----------------
extern "C" void kernel_launch(void* const* d_in, const int* in_sizes, int n_in,
                              void* d_out, int out_size, void* d_ws, size_t ws_size,
                              hipStream_t stream) {
  const float* x    = (const float*)d_in[0];
  const int*   edge = (const int*)d_in[1];
  const float* img  = (const float*)d_in[2];
  const int*   batch= (const int*)d_in[3];
  const float* W1   = (const float*)d_in[4];
  const float* b1   = (const float*)d_in[5];
  const float* W2   = (const float*)d_in[6];
  const float* b2   = (const float*)d_in[7];
  const float* Wm0  = (const float*)d_in[8];
  const float* bm0  = (const float*)d_in[9];
  const float* Wm1  = (const float*)d_in[10];
  const float* bm1  = (const float*)d_in[11];
  const float* Wmx  = (const float*)d_in[12];
  const float* bmx  = (const float*)d_in[13];
  const float* Wfc  = (const float*)d_in[14];
  const float* bfc  = (const float*)d_in[15];
  float* out = (float*)d_out;
  const int* srcp = edge;
  const int* dstp = edge + N_EDGES;

  // workspace carve-up (~110 MB total)
  char* ws = (char*)d_ws;
  size_t off = 0;
  auto alloc = [&](size_t bytes) {
    void* p = ws + off;
    off += (bytes + 255) & ~(size_t)255;
    return p;
  };
  int*   deg    = (int*)  alloc((size_t)N_NODES * 4);      // reused as csr cursor
  float* dinv   = (float*)alloc((size_t)N_NODES * 4);
  int*   rowptr = (int*)  alloc((size_t)(N_NODES + 1) * 4);
  int*   bsum   = (int*)  alloc((size_t)SCAN_BLOCKS * 4);
  int*   boff   = (int*)  alloc((size_t)SCAN_BLOCKS * 4);
  int*   csr    = (int*)  alloc((size_t)N_EDGES * 4);
  float* bufA   = (float*)alloc((size_t)N_NODES * 128 * 4);
  float* bufB   = (float*)alloc((size_t)N_NODES * 128 * 4);
  float* tmp1   = (float*)alloc(64 * 1024 * 4);
  float* x0     = (float*)alloc(64 * 64 * 4);
  float* g      = (float*)alloc(64 * 64 * 4);
  (void)ws_size; (void)in_sizes; (void)n_in; (void)out_size;

  // degrees -> dinv ; rowptr = scan(deg) ; CSR fill (deg reused as cursor)
  hipMemsetAsync(deg, 0, (size_t)N_NODES * 4, stream);
  k_deg  <<<(N_EDGES + 255) / 256, 256, 0, stream>>>(dstp, deg);
  k_dinv <<<(N_NODES + 255) / 256, 256, 0, stream>>>(deg, dinv);
  k_scan1<<<SCAN_BLOCKS, 512, 0, stream>>>(deg, bsum);
  k_scan2<<<1, 256, 0, stream>>>(bsum, boff);
  k_scan3<<<SCAN_BLOCKS, 512, 0, stream>>>(deg, boff, rowptr);
  hipMemsetAsync(deg, 0, (size_t)N_NODES * 4, stream);
  k_csr_fill<<<(N_EDGES + 255) / 256, 256, 0, stream>>>(srcp, dstp, rowptr, deg, csr);

  // image branch
  k_tmp1_init<<<(64 * 1024) / 256, 256, 0, stream>>>(bm0, tmp1);
  k_img_gemm <<<dim3(4, 196), 256, 0, stream>>>(img, Wm0, tmp1);
  k_img_gemm2<<<64, 256, 0, stream>>>(tmp1, Wm1, bm1, x0);

  // GCN layer 1
  k_gemm_node<128, 128, 128, false><<<(N_NODES + 127) / 128, 256, 0, stream>>>(
      x, W1, nullptr, bufA, N_NODES);
  k_agg_gather<128><<<(N_NODES + 7) / 8, 256, 0, stream>>>(bufA, dinv, rowptr, csr, bufB);

  // GCN layer 2 (bias+relu of layer 1 fused into GEMM's A-load)
  k_gemm_node<128, 64, 64, true><<<(N_NODES + 127) / 128, 128, 0, stream>>>(
      bufB, W2, b1, bufA, N_NODES);
  k_agg_gather<64><<<(N_NODES + 15) / 16, 256, 0, stream>>>(bufA, dinv, rowptr, csr, bufB);

  // pool + head
  k_pool <<<NGR, 256, 0, stream>>>(bufB, b2, batch, g);
  k_final<<<NGR, 64, 0, stream>>>(x0, g, Wmx, bmx, Wfc, bfc, out);
}

// Round 3
// 890.917 us; speedup vs baseline: 6.9010x; 2.5541x over previous
//
#include <hip/hip_runtime.h>
#include <math.h>

#define N_NODES 100000
#define N_EDGES 1600000
#define NGR 64
#define IMG_F 50176
#define NCLS 38
#define KSPLIT 98

typedef short bf16x8 __attribute__((ext_vector_type(8)));
typedef float f32x4 __attribute__((ext_vector_type(4)));

// fp32 pair -> packed bf16x2 (RNE)
__device__ __forceinline__ unsigned pk2(float a, float b) {
  unsigned ua = __float_as_uint(a), ub = __float_as_uint(b);
  ua = (ua + 0x7fffu + ((ua >> 16) & 1u)) >> 16;
  ub = (ub + 0x7fffu + ((ub >> 16) & 1u)) >> 16;
  return ua | (ub << 16);
}

// ---------------- small helpers ----------------
__device__ __forceinline__ int lower_bound_i(const int* __restrict__ a, int n, int v) {
  int lo = 0, hi = n;
  while (lo < hi) { int mid = (lo + hi) >> 1; if (a[mid] < v) lo = mid + 1; else hi = mid; }
  return lo;
}

__global__ void k_deg(const int* __restrict__ dst, int* __restrict__ deg) {
  int e = blockIdx.x * 256 + threadIdx.x;
  if (e < N_EDGES) atomicAdd(&deg[dst[e]], 1);
}

__global__ void k_dinv(const int* __restrict__ deg, float* __restrict__ dinv) {
  int n = blockIdx.x * 256 + threadIdx.x;
  if (n < N_NODES) dinv[n] = rsqrtf((float)deg[n] + 1.0f);
}

// ---------------- block scan: rowptr = exclusive_scan(deg) ----------------
#define SCAN_CHUNK 512
#define SCAN_BLOCKS ((N_NODES + SCAN_CHUNK - 1) / SCAN_CHUNK)  // 196

__global__ __launch_bounds__(512)
void k_scan1(const int* __restrict__ deg, int* __restrict__ bsum) {
  __shared__ int s[512];
  int t = threadIdx.x;
  int i = blockIdx.x * SCAN_CHUNK + t;
  s[t] = (i < N_NODES) ? deg[i] : 0;
  __syncthreads();
  for (int off = 256; off > 0; off >>= 1) {
    if (t < off) s[t] += s[t + off];
    __syncthreads();
  }
  if (t == 0) bsum[blockIdx.x] = s[0];
}

__global__ __launch_bounds__(256)
void k_scan2(const int* __restrict__ bsum, int* __restrict__ boff) {
  __shared__ int s[256];
  int t = threadIdx.x;
  s[t] = (t < SCAN_BLOCKS) ? bsum[t] : 0;
  __syncthreads();
  for (int off = 1; off < 256; off <<= 1) {
    int v = (t >= off) ? s[t - off] : 0;
    __syncthreads();
    s[t] += v;
    __syncthreads();
  }
  if (t < SCAN_BLOCKS) boff[t] = (t == 0) ? 0 : s[t - 1];
}

__global__ __launch_bounds__(512)
void k_scan3(const int* __restrict__ deg, const int* __restrict__ boff,
             int* __restrict__ rowptr) {
  __shared__ int s[512];
  int t = threadIdx.x;
  int i = blockIdx.x * SCAN_CHUNK + t;
  int d = (i < N_NODES) ? deg[i] : 0;
  s[t] = d;
  __syncthreads();
  for (int off = 1; off < 512; off <<= 1) {
    int v = (t >= off) ? s[t - off] : 0;
    __syncthreads();
    s[t] += v;
    __syncthreads();
  }
  if (i < N_NODES) rowptr[i] = boff[blockIdx.x] + s[t] - d;
  if (blockIdx.x == 0 && t == 0) rowptr[N_NODES] = N_EDGES;
}

__global__ void k_csr_fill(const int* __restrict__ src, const int* __restrict__ dst,
                           const int* __restrict__ rowptr, int* __restrict__ cur,
                           int* __restrict__ csr_src) {
  int e = blockIdx.x * 256 + threadIdx.x;
  if (e >= N_EDGES) return;
  int d = dst[e];
  int pos = rowptr[d] + atomicAdd(&cur[d], 1);
  csr_src[pos] = src[e];
}

// ---------------- GCN aggregation (gather, atomic-free) ----------------
template<int F>
__global__ __launch_bounds__(256)
void k_agg_gather(const float* __restrict__ h, const float* __restrict__ dinv,
                  const int* __restrict__ rowptr, const int* __restrict__ csr_src,
                  float* __restrict__ out) {
  constexpr int L = F / 4;
  constexpr int NPB = 256 / L;
  int n = blockIdx.x * NPB + threadIdx.x / L;
  int lane = threadIdx.x % L;
  if (n >= N_NODES) return;
  float dn = dinv[n];
  float4 v = *(const float4*)&h[(size_t)n * F + lane * 4];
  float sc = dn * dn;
  float4 acc = make_float4(v.x * sc, v.y * sc, v.z * sc, v.w * sc);
  int lo = rowptr[n], hi = rowptr[n + 1];
  int i = lo;
  for (; i + 1 < hi; i += 2) {
    int s0 = csr_src[i], s1 = csr_src[i + 1];
    float c0 = dinv[s0] * dn, c1 = dinv[s1] * dn;
    float4 u0 = *(const float4*)&h[(size_t)s0 * F + lane * 4];
    float4 u1 = *(const float4*)&h[(size_t)s1 * F + lane * 4];
    acc.x = fmaf(u0.x, c0, acc.x); acc.y = fmaf(u0.y, c0, acc.y);
    acc.z = fmaf(u0.z, c0, acc.z); acc.w = fmaf(u0.w, c0, acc.w);
    acc.x = fmaf(u1.x, c1, acc.x); acc.y = fmaf(u1.y, c1, acc.y);
    acc.z = fmaf(u1.z, c1, acc.z); acc.w = fmaf(u1.w, c1, acc.w);
  }
  if (i < hi) {
    int s0 = csr_src[i];
    float c0 = dinv[s0] * dn;
    float4 u0 = *(const float4*)&h[(size_t)s0 * F + lane * 4];
    acc.x = fmaf(u0.x, c0, acc.x); acc.y = fmaf(u0.y, c0, acc.y);
    acc.z = fmaf(u0.z, c0, acc.z); acc.w = fmaf(u0.w, c0, acc.w);
  }
  *(float4*)&out[(size_t)n * F + lane * 4] = acc;
}

// ---------------- img GEMM: bf16 MFMA split-K, NO atomics ----------------
// partial[ks][64][1024] = A[64, kchunk] @ B[kchunk, 128-coltile]
// LDS stored in MFMA-fragment order (8 bf16 along k per 16B chunk), kq-XOR
// swizzled so fragment ds_read_b128 are conflict-free.
__global__ __launch_bounds__(256)
void k_img_mfma(const float* __restrict__ A, const float* __restrict__ B,
                float* __restrict__ partial) {
  __shared__ __align__(16) short Al[512 * 8];    // 8 KB  [kst2][kq4][rt4][rr16]
  __shared__ __align__(16) short Bl[1024 * 8];   // 16 KB [kst2][kq4][ct8][col16]
  const int tid = threadIdx.x;
  const int l = tid & 63, w = tid >> 6;
  const int col0 = blockIdx.x * 128;
  const int kbase = blockIdx.y * 512;
  const int kq_l = l >> 4, rr_l = l & 15;
  f32x4 acc[8];
#pragma unroll
  for (int ct = 0; ct < 8; ct++) acc[ct] = (f32x4)(0.f);

  for (int st = 0; st < 8; st++) {
    int k0 = kbase + st * 64;
    __syncthreads();
    // stage A: 64 rows x 64 k (fp32) -> bf16 frag chunks
#pragma unroll
    for (int it = 0; it < 2; it++) {
      int c = tid + it * 256;
      int r = c >> 3, ko = c & 7;
      const float* ap = &A[(size_t)r * IMG_F + k0 + ko * 8];
      float4 f0 = *(const float4*)ap;
      float4 f1 = *(const float4*)(ap + 4);
      int kst = ko >> 2, kq = ko & 3, rt = r >> 4, rr = r & 15;
      int ci = ((kst * 4 + kq) * 4 + (rt ^ kq)) * 16 + rr;
      uint4 u = make_uint4(pk2(f0.x, f0.y), pk2(f0.z, f0.w),
                           pk2(f1.x, f1.y), pk2(f1.z, f1.w));
      *(uint4*)&Al[ci * 8] = u;
    }
    // stage B: 64 k-rows x 128 cols; micro-tile 8k x 4col per thread (transpose)
    {
      int col4 = tid & 31, ko = tid >> 5;
      const float* bp = &B[(size_t)(k0 + ko * 8) * 1024 + col0 + col4 * 4];
      float fb[8][4];
#pragma unroll
      for (int i2 = 0; i2 < 8; i2++)
        *(float4*)&fb[i2][0] = *(const float4*)(bp + (size_t)i2 * 1024);
      int kst = ko >> 2, kq = ko & 3;
#pragma unroll
      for (int c2 = 0; c2 < 4; c2++) {
        int col = col4 * 4 + c2;
        int ct = col >> 4, colin = col & 15;
        int ci = ((kst * 4 + kq) * 8 + (ct ^ kq)) * 16 + colin;
        uint4 u = make_uint4(pk2(fb[0][c2], fb[1][c2]), pk2(fb[2][c2], fb[3][c2]),
                             pk2(fb[4][c2], fb[5][c2]), pk2(fb[6][c2], fb[7][c2]));
        *(uint4*)&Bl[ci * 8] = u;
      }
    }
    __syncthreads();
#pragma unroll
    for (int kst = 0; kst < 2; kst++) {
      bf16x8 af = *(bf16x8*)&Al[(((kst * 4 + kq_l) * 4 + (w ^ kq_l)) * 16 + rr_l) * 8];
#pragma unroll
      for (int ct = 0; ct < 8; ct++) {
        bf16x8 bf = *(bf16x8*)&Bl[(((kst * 4 + kq_l) * 8 + (ct ^ kq_l)) * 16 + rr_l) * 8];
        acc[ct] = __builtin_amdgcn_mfma_f32_16x16x32_bf16(af, bf, acc[ct], 0, 0, 0);
      }
    }
  }
  // epilogue: C/D layout col=lane&15, row=(lane>>4)*4+reg (m89-verified)
  float* P = partial + (size_t)blockIdx.y * 64 * 1024;
#pragma unroll
  for (int ct = 0; ct < 8; ct++)
#pragma unroll
    for (int rg = 0; rg < 4; rg++) {
      int row = w * 16 + (l >> 4) * 4 + rg;
      int col = col0 + ct * 16 + (l & 15);
      P[row * 1024 + col] = acc[ct][rg];
    }
}

__global__ __launch_bounds__(256)
void k_img_reduce(const float* __restrict__ partial, const float* __restrict__ bm0,
                  float* __restrict__ tmp1) {
  int i = blockIdx.x * 256 + threadIdx.x;  // 65536
  float s = bm0[i & 1023];
  for (int ks = 0; ks < KSPLIT; ks++) s += partial[(size_t)ks * 65536 + i];
  tmp1[i] = s;
}

// x0[64,64] = tmp1[64,1024] @ Wm1[1024,64] + bm1
__global__ __launch_bounds__(256)
void k_img_gemm2(const float* __restrict__ T, const float* __restrict__ Wm1,
                 const float* __restrict__ bm1, float* __restrict__ x0) {
  int r = blockIdx.x;
  int c = threadIdx.x & 63;
  int q = threadIdx.x >> 6;
  float acc = 0.f;
#pragma unroll 8
  for (int k = q; k < 1024; k += 4)
    acc = fmaf(T[r * 1024 + k], Wm1[k * 64 + c], acc);
  __shared__ float red[4][64];
  red[q][c] = acc;
  __syncthreads();
  if (q == 0) x0[r * 64 + c] = red[0][c] + red[1][c] + red[2][c] + red[3][c] + bm1[c];
}

// ---------------- node GEMM: C[M,N] = act(A[M,128]) @ W[128,N], bf16 MFMA ----
// BM=64 rows/block, all of K=128 staged once; wave w owns row-tile w.
template<int N, bool RELU_BIAS>
__global__ __launch_bounds__(256)
void k_gcn_mfma(const float* __restrict__ A, const float* __restrict__ W,
                const float* __restrict__ abias, float* __restrict__ C, int M) {
  constexpr int NT16 = N / 16;
  __shared__ __align__(16) short Al[1024 * 8];          // 16 KB [kst4][kq4][rt4][rr16]
  __shared__ __align__(16) short Wl[256 * NT16 * 8];    // N=128:32KB, N=64:16KB
  const int tid = threadIdx.x;
  const int l = tid & 63, w = tid >> 6;
  const int row0 = blockIdx.x * 64;
  const int kq_l = l >> 4, rr_l = l & 15;

  // stage A (rows row0..row0+63, K=128) with optional bias+relu
#pragma unroll
  for (int it = 0; it < 4; it++) {
    int c = tid + it * 256;
    int r = c >> 4, ko = c & 15;
    int row = row0 + r;
    float4 f0 = make_float4(0.f, 0.f, 0.f, 0.f), f1 = f0;
    if (row < M) {
      const float* ap = &A[(size_t)row * 128 + ko * 8];
      f0 = *(const float4*)ap;
      f1 = *(const float4*)(ap + 4);
      if (RELU_BIAS) {
        const float* bp = &abias[ko * 8];
        f0.x = fmaxf(f0.x + bp[0], 0.f); f0.y = fmaxf(f0.y + bp[1], 0.f);
        f0.z = fmaxf(f0.z + bp[2], 0.f); f0.w = fmaxf(f0.w + bp[3], 0.f);
        f1.x = fmaxf(f1.x + bp[4], 0.f); f1.y = fmaxf(f1.y + bp[5], 0.f);
        f1.z = fmaxf(f1.z + bp[6], 0.f); f1.w = fmaxf(f1.w + bp[7], 0.f);
      }
    }
    int kst = ko >> 2, kq = ko & 3, rt = r >> 4, rr = r & 15;
    int ci = ((kst * 4 + kq) * 4 + (rt ^ kq)) * 16 + rr;
    uint4 u = make_uint4(pk2(f0.x, f0.y), pk2(f0.z, f0.w),
                         pk2(f1.x, f1.y), pk2(f1.z, f1.w));
    *(uint4*)&Al[ci * 8] = u;
  }
  // stage W (128 x N) via 8k x 4col micro-tiles (transpose to frag order)
#pragma unroll
  for (int it = 0; it < (N == 128 ? 2 : 1); it++) {
    int mt = tid + it * 256;
    int col4 = mt % (N / 4), ko = mt / (N / 4);
    float fb[8][4];
#pragma unroll
    for (int i2 = 0; i2 < 8; i2++)
      *(float4*)&fb[i2][0] = *(const float4*)&W[(size_t)(ko * 8 + i2) * N + col4 * 4];
    int kst = ko >> 2, kq = ko & 3;
#pragma unroll
    for (int c2 = 0; c2 < 4; c2++) {
      int col = col4 * 4 + c2;
      int ct = col >> 4, colin = col & 15;
      int ci = ((kst * 4 + kq) * NT16 + (ct ^ kq)) * 16 + colin;
      uint4 u = make_uint4(pk2(fb[0][c2], fb[1][c2]), pk2(fb[2][c2], fb[3][c2]),
                           pk2(fb[4][c2], fb[5][c2]), pk2(fb[6][c2], fb[7][c2]));
      *(uint4*)&Wl[ci * 8] = u;
    }
  }
  __syncthreads();

  f32x4 acc[NT16];
#pragma unroll
  for (int ct = 0; ct < NT16; ct++) acc[ct] = (f32x4)(0.f);
#pragma unroll
  for (int kst = 0; kst < 4; kst++) {
    bf16x8 af = *(bf16x8*)&Al[(((kst * 4 + kq_l) * 4 + (w ^ kq_l)) * 16 + rr_l) * 8];
#pragma unroll
    for (int ct = 0; ct < NT16; ct++) {
      bf16x8 bf = *(bf16x8*)&Wl[(((kst * 4 + kq_l) * NT16 + (ct ^ kq_l)) * 16 + rr_l) * 8];
      acc[ct] = __builtin_amdgcn_mfma_f32_16x16x32_bf16(af, bf, acc[ct], 0, 0, 0);
    }
  }
#pragma unroll
  for (int ct = 0; ct < NT16; ct++)
#pragma unroll
    for (int rg = 0; rg < 4; rg++) {
      int row = row0 + w * 16 + (l >> 4) * 4 + rg;
      int col = ct * 16 + (l & 15);
      if (row < M) C[(size_t)row * N + col] = acc[ct][rg];
    }
}

// ---------------- pool ----------------
__global__ __launch_bounds__(256)
void k_pool(const float* __restrict__ h2, const float* __restrict__ b2,
            const int* __restrict__ batch, float* __restrict__ g) {
  int b = blockIdx.x;
  int f = threadIdx.x & 63;
  int q = threadIdx.x >> 6;
  int lo = lower_bound_i(batch, N_NODES, b);
  int hi = lower_bound_i(batch, N_NODES, b + 1);
  float bias = b2[f];
  float acc = 0.f;
  for (int i = lo + q; i < hi; i += 4)
    acc += fmaxf(h2[(size_t)i * 64 + f] + bias, 0.f);
  __shared__ float red[4][64];
  red[q][f] = acc;
  __syncthreads();
  if (q == 0) g[b * 64 + f] = red[0][f] + red[1][f] + red[2][f] + red[3][f];
}

// ---------------- head ----------------
__global__ __launch_bounds__(64)
void k_final(const float* __restrict__ x0, const float* __restrict__ g,
             const float* __restrict__ Wmx, const float* __restrict__ bmx,
             const float* __restrict__ Wfc, const float* __restrict__ bfc,
             float* __restrict__ out) {
  int r = blockIdx.x;
  int c = threadIdx.x;
  __shared__ float sx[128];
  __shared__ float slog[NCLS];
  __shared__ float sred;
  float acc = bmx[c];
#pragma unroll 8
  for (int k = 0; k < 64; k++) acc = fmaf(g[r * 64 + k], Wmx[k * 64 + c], acc);
  sx[64 + c] = acc;
  sx[c] = x0[r * 64 + c];
  __syncthreads();
  float lg = 0.f;
  if (c < NCLS) {
    lg = bfc[c];
#pragma unroll 8
    for (int k = 0; k < 128; k++) lg = fmaf(sx[k], Wfc[k * NCLS + c], lg);
    slog[c] = lg;
  }
  __syncthreads();
  if (c == 0) {
    float m = -1e30f;
    for (int j = 0; j < NCLS; j++) m = fmaxf(m, slog[j]);
    float s = 0.f;
    for (int j = 0; j < NCLS; j++) s += expf(slog[j] - m);
    sred = m + logf(s);
  }
  __syncthreads();
  if (c < NCLS) out[r * NCLS + c] = lg - sred;
}

// ---------------- launch ----------------
extern "C" void kernel_launch(void* const* d_in, const int* in_sizes, int n_in,
                              void* d_out, int out_size, void* d_ws, size_t ws_size,
                              hipStream_t stream) {
  const float* x    = (const float*)d_in[0];
  const int*   edge = (const int*)d_in[1];
  const float* img  = (const float*)d_in[2];
  const int*   batch= (const int*)d_in[3];
  const float* W1   = (const float*)d_in[4];
  const float* b1   = (const float*)d_in[5];
  const float* W2   = (const float*)d_in[6];
  const float* b2   = (const float*)d_in[7];
  const float* Wm0  = (const float*)d_in[8];
  const float* bm0  = (const float*)d_in[9];
  const float* Wm1  = (const float*)d_in[10];
  const float* bm1  = (const float*)d_in[11];
  const float* Wmx  = (const float*)d_in[12];
  const float* bmx  = (const float*)d_in[13];
  const float* Wfc  = (const float*)d_in[14];
  const float* bfc  = (const float*)d_in[15];
  float* out = (float*)d_out;
  const int* srcp = edge;
  const int* dstp = edge + N_EDGES;

  char* ws = (char*)d_ws;
  size_t off = 0;
  auto alloc = [&](size_t bytes) {
    void* p = ws + off;
    off += (bytes + 255) & ~(size_t)255;
    return p;
  };
  int*   deg    = (int*)  alloc((size_t)N_NODES * 4);
  float* dinv   = (float*)alloc((size_t)N_NODES * 4);
  int*   rowptr = (int*)  alloc((size_t)(N_NODES + 1) * 4);
  int*   bsum   = (int*)  alloc((size_t)SCAN_BLOCKS * 4);
  int*   boff   = (int*)  alloc((size_t)SCAN_BLOCKS * 4);
  int*   csr    = (int*)  alloc((size_t)N_EDGES * 4);
  float* bufA   = (float*)alloc((size_t)N_NODES * 128 * 4);
  float* bufB   = (float*)alloc((size_t)N_NODES * 128 * 4);
  float* tmp1   = (float*)alloc(64 * 1024 * 4);
  float* x0     = (float*)alloc(64 * 64 * 4);
  float* g      = (float*)alloc(64 * 64 * 4);
  float* partial = bufB;  // 25.7 MB, used only before agg1 writes bufB (stream-ordered)
  (void)ws_size; (void)in_sizes; (void)n_in; (void)out_size;

  // degrees -> dinv ; rowptr ; CSR (deg reused as cursor)
  hipMemsetAsync(deg, 0, (size_t)N_NODES * 4, stream);
  k_deg  <<<(N_EDGES + 255) / 256, 256, 0, stream>>>(dstp, deg);
  k_dinv <<<(N_NODES + 255) / 256, 256, 0, stream>>>(deg, dinv);
  k_scan1<<<SCAN_BLOCKS, 512, 0, stream>>>(deg, bsum);
  k_scan2<<<1, 256, 0, stream>>>(bsum, boff);
  k_scan3<<<SCAN_BLOCKS, 512, 0, stream>>>(deg, boff, rowptr);
  hipMemsetAsync(deg, 0, (size_t)N_NODES * 4, stream);
  k_csr_fill<<<(N_EDGES + 255) / 256, 256, 0, stream>>>(srcp, dstp, rowptr, deg, csr);

  // image branch (bf16 MFMA split-K, partials + reduce; no atomics)
  k_img_mfma  <<<dim3(8, KSPLIT), 256, 0, stream>>>(img, Wm0, partial);
  k_img_reduce<<<256, 256, 0, stream>>>(partial, bm0, tmp1);
  k_img_gemm2 <<<64, 256, 0, stream>>>(tmp1, Wm1, bm1, x0);

  // GCN layer 1 (bf16 MFMA), then gather-agg
  k_gcn_mfma<128, false><<<(N_NODES + 63) / 64, 256, 0, stream>>>(
      x, W1, nullptr, bufA, N_NODES);
  k_agg_gather<128><<<(N_NODES + 7) / 8, 256, 0, stream>>>(bufA, dinv, rowptr, csr, bufB);

  // GCN layer 2 (bias+relu of layer 1 fused into A-staging)
  k_gcn_mfma<64, true><<<(N_NODES + 63) / 64, 256, 0, stream>>>(
      bufB, W2, b1, bufA, N_NODES);
  k_agg_gather<64><<<(N_NODES + 15) / 16, 256, 0, stream>>>(bufA, dinv, rowptr, csr, bufB);

  // pool + head
  k_pool <<<NGR, 256, 0, stream>>>(bufB, b2, batch, g);
  k_final<<<NGR, 64, 0, stream>>>(x0, g, Wmx, bmx, Wfc, bfc, out);
}

// Round 4
// 787.690 us; speedup vs baseline: 7.8054x; 1.1311x over previous
//
#include <hip/hip_runtime.h>
#include <math.h>

#define N_NODES 100000
#define N_EDGES 1600000
#define NGR 64
#define IMG_F 50176
#define NCLS 38
#define KSPLIT 98

typedef short bf16x8 __attribute__((ext_vector_type(8)));
typedef float f32x4 __attribute__((ext_vector_type(4)));
typedef unsigned int uint;

// fp32 pair -> packed bf16x2 (RNE)
__device__ __forceinline__ uint pk2(float a, float b) {
  uint ua = __float_as_uint(a), ub = __float_as_uint(b);
  ua = (ua + 0x7fffu + ((ua >> 16) & 1u)) >> 16;
  ub = (ub + 0x7fffu + ((ub >> 16) & 1u)) >> 16;
  return ua | (ub << 16);
}
__device__ __forceinline__ unsigned short f2bf(float x) {
  uint u = __float_as_uint(x);
  u = (u + 0x7fffu + ((u >> 16) & 1u)) >> 16;
  return (unsigned short)u;
}
__device__ __forceinline__ float bflo(uint u) { return __uint_as_float(u << 16); }
__device__ __forceinline__ float bfhi(uint u) { return __uint_as_float(u & 0xffff0000u); }

// ---------------- small helpers ----------------
__device__ __forceinline__ int lower_bound_i(const int* __restrict__ a, int n, int v) {
  int lo = 0, hi = n;
  while (lo < hi) { int mid = (lo + hi) >> 1; if (a[mid] < v) lo = mid + 1; else hi = mid; }
  return lo;
}

__global__ void k_deg(const int* __restrict__ dst, int* __restrict__ deg) {
  int e = blockIdx.x * 256 + threadIdx.x;
  if (e < N_EDGES) atomicAdd(&deg[dst[e]], 1);
}

__global__ void k_dinv(const int* __restrict__ deg, float* __restrict__ dinv) {
  int n = blockIdx.x * 256 + threadIdx.x;
  if (n < N_NODES) dinv[n] = rsqrtf((float)deg[n] + 1.0f);
}

// ---------------- block scan: rowptr = exclusive_scan(deg) ----------------
#define SCAN_CHUNK 512
#define SCAN_BLOCKS ((N_NODES + SCAN_CHUNK - 1) / SCAN_CHUNK)  // 196

__global__ __launch_bounds__(512)
void k_scan1(const int* __restrict__ deg, int* __restrict__ bsum) {
  __shared__ int s[512];
  int t = threadIdx.x;
  int i = blockIdx.x * SCAN_CHUNK + t;
  s[t] = (i < N_NODES) ? deg[i] : 0;
  __syncthreads();
  for (int off = 256; off > 0; off >>= 1) {
    if (t < off) s[t] += s[t + off];
    __syncthreads();
  }
  if (t == 0) bsum[blockIdx.x] = s[0];
}

__global__ __launch_bounds__(256)
void k_scan2(const int* __restrict__ bsum, int* __restrict__ boff) {
  __shared__ int s[256];
  int t = threadIdx.x;
  s[t] = (t < SCAN_BLOCKS) ? bsum[t] : 0;
  __syncthreads();
  for (int off = 1; off < 256; off <<= 1) {
    int v = (t >= off) ? s[t - off] : 0;
    __syncthreads();
    s[t] += v;
    __syncthreads();
  }
  if (t < SCAN_BLOCKS) boff[t] = (t == 0) ? 0 : s[t - 1];
}

__global__ __launch_bounds__(512)
void k_scan3(const int* __restrict__ deg, const int* __restrict__ boff,
             int* __restrict__ rowptr) {
  __shared__ int s[512];
  int t = threadIdx.x;
  int i = blockIdx.x * SCAN_CHUNK + t;
  int d = (i < N_NODES) ? deg[i] : 0;
  s[t] = d;
  __syncthreads();
  for (int off = 1; off < 512; off <<= 1) {
    int v = (t >= off) ? s[t - off] : 0;
    __syncthreads();
    s[t] += v;
    __syncthreads();
  }
  if (i < N_NODES) rowptr[i] = boff[blockIdx.x] + s[t] - d;
  if (blockIdx.x == 0 && t == 0) rowptr[N_NODES] = N_EDGES;
}

__global__ void k_csr_fill(const int* __restrict__ src, const int* __restrict__ dst,
                           const int* __restrict__ rowptr, int* __restrict__ cur,
                           int* __restrict__ csr_src) {
  int e = blockIdx.x * 256 + threadIdx.x;
  if (e >= N_EDGES) return;
  int d = dst[e];
  int pos = rowptr[d] + atomicAdd(&cur[d], 1);
  csr_src[pos] = src[e];
}

// ---------------- GCN aggregation (gather, bf16, atomic-free) ----------------
// h holds h'[n] = h_lin[n]*dinv[n] (bf16). out[n] = bf16(dinv[n]*(h'[n]+sum h'[src])).
// 16 lanes per node; VEC bf16 per lane (F=128: 8, F=64: 4).
template<int F, int VEC>
__global__ __launch_bounds__(256)
void k_agg_bf16(const unsigned short* __restrict__ h, const float* __restrict__ dinv,
                const int* __restrict__ rowptr, const int* __restrict__ csr_src,
                unsigned short* __restrict__ out) {
  constexpr int L = F / VEC;    // 16
  constexpr int NPB = 256 / L;  // 16
  constexpr int NU = VEC / 2;   // uints per lane
  int n = blockIdx.x * NPB + threadIdx.x / L;
  int lane = threadIdx.x % L;
  if (n >= N_NODES) return;
  const uint* hu = (const uint*)h;
  const int rs = F / 2;  // uints per feature row
  float acc[VEC];
  uint r0[NU];
  if constexpr (VEC == 8) *(uint4*)r0 = *(const uint4*)&hu[(size_t)n * rs + lane * NU];
  else                    *(uint2*)r0 = *(const uint2*)&hu[(size_t)n * rs + lane * NU];
#pragma unroll
  for (int j = 0; j < NU; j++) { acc[2*j] = bflo(r0[j]); acc[2*j+1] = bfhi(r0[j]); }
  int lo = rowptr[n], hi = rowptr[n + 1];
  int i = lo;
  for (; i + 1 < hi; i += 2) {
    int s0 = csr_src[i], s1 = csr_src[i + 1];
    uint a0[NU], a1[NU];
    if constexpr (VEC == 8) {
      *(uint4*)a0 = *(const uint4*)&hu[(size_t)s0 * rs + lane * NU];
      *(uint4*)a1 = *(const uint4*)&hu[(size_t)s1 * rs + lane * NU];
    } else {
      *(uint2*)a0 = *(const uint2*)&hu[(size_t)s0 * rs + lane * NU];
      *(uint2*)a1 = *(const uint2*)&hu[(size_t)s1 * rs + lane * NU];
    }
#pragma unroll
    for (int j = 0; j < NU; j++) {
      acc[2*j]   += bflo(a0[j]); acc[2*j+1] += bfhi(a0[j]);
      acc[2*j]   += bflo(a1[j]); acc[2*j+1] += bfhi(a1[j]);
    }
  }
  if (i < hi) {
    int s0 = csr_src[i];
    uint a0[NU];
    if constexpr (VEC == 8) *(uint4*)a0 = *(const uint4*)&hu[(size_t)s0 * rs + lane * NU];
    else                    *(uint2*)a0 = *(const uint2*)&hu[(size_t)s0 * rs + lane * NU];
#pragma unroll
    for (int j = 0; j < NU; j++) { acc[2*j] += bflo(a0[j]); acc[2*j+1] += bfhi(a0[j]); }
  }
  float dn = dinv[n];
  uint o[NU];
#pragma unroll
  for (int j = 0; j < NU; j++) o[j] = pk2(dn * acc[2*j], dn * acc[2*j+1]);
  uint* op = (uint*)out + (size_t)n * rs + lane * NU;
  if constexpr (VEC == 8) *(uint4*)op = *(uint4*)o;
  else                    *(uint2*)op = *(uint2*)o;
}

// ---------------- img GEMM: bf16 MFMA split-K, NO atomics ----------------
__global__ __launch_bounds__(256)
void k_img_mfma(const float* __restrict__ A, const float* __restrict__ B,
                float* __restrict__ partial) {
  __shared__ __align__(16) short Al[512 * 8];    // 8 KB
  __shared__ __align__(16) short Bl[1024 * 8];   // 16 KB
  const int tid = threadIdx.x;
  const int l = tid & 63, w = tid >> 6;
  const int col0 = blockIdx.x * 128;
  const int kbase = blockIdx.y * 512;
  const int kq_l = l >> 4, rr_l = l & 15;
  f32x4 acc[8];
#pragma unroll
  for (int ct = 0; ct < 8; ct++) acc[ct] = (f32x4)(0.f);

  for (int st = 0; st < 8; st++) {
    int k0 = kbase + st * 64;
    __syncthreads();
#pragma unroll
    for (int it = 0; it < 2; it++) {
      int c = tid + it * 256;
      int r = c >> 3, ko = c & 7;
      const float* ap = &A[(size_t)r * IMG_F + k0 + ko * 8];
      float4 f0 = *(const float4*)ap;
      float4 f1 = *(const float4*)(ap + 4);
      int kst = ko >> 2, kq = ko & 3, rt = r >> 4, rr = r & 15;
      int ci = ((kst * 4 + kq) * 4 + (rt ^ kq)) * 16 + rr;
      uint4 u = make_uint4(pk2(f0.x, f0.y), pk2(f0.z, f0.w),
                           pk2(f1.x, f1.y), pk2(f1.z, f1.w));
      *(uint4*)&Al[ci * 8] = u;
    }
    {
      int col4 = tid & 31, ko = tid >> 5;
      const float* bp = &B[(size_t)(k0 + ko * 8) * 1024 + col0 + col4 * 4];
      float fb[8][4];
#pragma unroll
      for (int i2 = 0; i2 < 8; i2++)
        *(float4*)&fb[i2][0] = *(const float4*)(bp + (size_t)i2 * 1024);
      int kst = ko >> 2, kq = ko & 3;
#pragma unroll
      for (int c2 = 0; c2 < 4; c2++) {
        int col = col4 * 4 + c2;
        int ct = col >> 4, colin = col & 15;
        int ci = ((kst * 4 + kq) * 8 + (ct ^ kq)) * 16 + colin;
        uint4 u = make_uint4(pk2(fb[0][c2], fb[1][c2]), pk2(fb[2][c2], fb[3][c2]),
                             pk2(fb[4][c2], fb[5][c2]), pk2(fb[6][c2], fb[7][c2]));
        *(uint4*)&Bl[ci * 8] = u;
      }
    }
    __syncthreads();
#pragma unroll
    for (int kst = 0; kst < 2; kst++) {
      bf16x8 af = *(bf16x8*)&Al[(((kst * 4 + kq_l) * 4 + (w ^ kq_l)) * 16 + rr_l) * 8];
#pragma unroll
      for (int ct = 0; ct < 8; ct++) {
        bf16x8 bf = *(bf16x8*)&Bl[(((kst * 4 + kq_l) * 8 + (ct ^ kq_l)) * 16 + rr_l) * 8];
        acc[ct] = __builtin_amdgcn_mfma_f32_16x16x32_bf16(af, bf, acc[ct], 0, 0, 0);
      }
    }
  }
  float* P = partial + (size_t)blockIdx.y * 64 * 1024;
#pragma unroll
  for (int ct = 0; ct < 8; ct++)
#pragma unroll
    for (int rg = 0; rg < 4; rg++) {
      int row = w * 16 + (l >> 4) * 4 + rg;
      int col = col0 + ct * 16 + (l & 15);
      P[row * 1024 + col] = acc[ct][rg];
    }
}

__global__ __launch_bounds__(256)
void k_img_reduce(const float* __restrict__ partial, const float* __restrict__ bm0,
                  float* __restrict__ tmp1) {
  int i = blockIdx.x * 256 + threadIdx.x;
  float s = bm0[i & 1023];
  for (int ks = 0; ks < KSPLIT; ks++) s += partial[(size_t)ks * 65536 + i];
  tmp1[i] = s;
}

__global__ __launch_bounds__(256)
void k_img_gemm2(const float* __restrict__ T, const float* __restrict__ Wm1,
                 const float* __restrict__ bm1, float* __restrict__ x0) {
  int r = blockIdx.x;
  int c = threadIdx.x & 63;
  int q = threadIdx.x >> 6;
  float acc = 0.f;
#pragma unroll 8
  for (int k = q; k < 1024; k += 4)
    acc = fmaf(T[r * 1024 + k], Wm1[k * 64 + c], acc);
  __shared__ float red[4][64];
  red[q][c] = acc;
  __syncthreads();
  if (q == 0) x0[r * 64 + c] = red[0][c] + red[1][c] + red[2][c] + red[3][c] + bm1[c];
}

// ---------------- node GEMM: C[M,N] = dinv[row]*(act(A[M,128]) @ W[128,N]), bf16
template<int N, bool RELU_BIAS, bool BF16_IN>
__global__ __launch_bounds__(256)
void k_gcn_mfma(const void* __restrict__ Ain, const float* __restrict__ W,
                const float* __restrict__ abias, const float* __restrict__ dinv,
                unsigned short* __restrict__ C, int M) {
  constexpr int NT16 = N / 16;
  __shared__ __align__(16) short Al[1024 * 8];
  __shared__ __align__(16) short Wl[256 * NT16 * 8];
  const int tid = threadIdx.x;
  const int l = tid & 63, w = tid >> 6;
  const int row0 = blockIdx.x * 64;
  const int kq_l = l >> 4, rr_l = l & 15;

#pragma unroll
  for (int it = 0; it < 4; it++) {
    int c = tid + it * 256;
    int r = c >> 4, ko = c & 15;
    int row = row0 + r;
    float f[8] = {0.f, 0.f, 0.f, 0.f, 0.f, 0.f, 0.f, 0.f};
    if (row < M) {
      if constexpr (BF16_IN) {
        const uint* ap = (const uint*)Ain + (size_t)row * 64 + ko * 4;
        uint4 u = *(const uint4*)ap;
        f[0] = bflo(u.x); f[1] = bfhi(u.x); f[2] = bflo(u.y); f[3] = bfhi(u.y);
        f[4] = bflo(u.z); f[5] = bfhi(u.z); f[6] = bflo(u.w); f[7] = bfhi(u.w);
      } else {
        const float* ap = (const float*)Ain + (size_t)row * 128 + ko * 8;
        *(float4*)&f[0] = *(const float4*)ap;
        *(float4*)&f[4] = *(const float4*)(ap + 4);
      }
      if (RELU_BIAS) {
        const float* bp = &abias[ko * 8];
#pragma unroll
        for (int j = 0; j < 8; j++) f[j] = fmaxf(f[j] + bp[j], 0.f);
      }
    }
    int kst = ko >> 2, kq = ko & 3, rt = r >> 4, rr = r & 15;
    int ci = ((kst * 4 + kq) * 4 + (rt ^ kq)) * 16 + rr;
    uint4 u = make_uint4(pk2(f[0], f[1]), pk2(f[2], f[3]),
                         pk2(f[4], f[5]), pk2(f[6], f[7]));
    *(uint4*)&Al[ci * 8] = u;
  }
#pragma unroll
  for (int it = 0; it < (N == 128 ? 2 : 1); it++) {
    int mt = tid + it * 256;
    int col4 = mt % (N / 4), ko = mt / (N / 4);
    float fb[8][4];
#pragma unroll
    for (int i2 = 0; i2 < 8; i2++)
      *(float4*)&fb[i2][0] = *(const float4*)&W[(size_t)(ko * 8 + i2) * N + col4 * 4];
    int kst = ko >> 2, kq = ko & 3;
#pragma unroll
    for (int c2 = 0; c2 < 4; c2++) {
      int col = col4 * 4 + c2;
      int ct = col >> 4, colin = col & 15;
      int ci = ((kst * 4 + kq) * NT16 + (ct ^ kq)) * 16 + colin;
      uint4 u = make_uint4(pk2(fb[0][c2], fb[1][c2]), pk2(fb[2][c2], fb[3][c2]),
                           pk2(fb[4][c2], fb[5][c2]), pk2(fb[6][c2], fb[7][c2]));
      *(uint4*)&Wl[ci * 8] = u;
    }
  }
  __syncthreads();

  f32x4 acc[NT16];
#pragma unroll
  for (int ct = 0; ct < NT16; ct++) acc[ct] = (f32x4)(0.f);
#pragma unroll
  for (int kst = 0; kst < 4; kst++) {
    bf16x8 af = *(bf16x8*)&Al[(((kst * 4 + kq_l) * 4 + (w ^ kq_l)) * 16 + rr_l) * 8];
#pragma unroll
    for (int ct = 0; ct < NT16; ct++) {
      bf16x8 bf = *(bf16x8*)&Wl[(((kst * 4 + kq_l) * NT16 + (ct ^ kq_l)) * 16 + rr_l) * 8];
      acc[ct] = __builtin_amdgcn_mfma_f32_16x16x32_bf16(af, bf, acc[ct], 0, 0, 0);
    }
  }
#pragma unroll
  for (int rg = 0; rg < 4; rg++) {
    int row = row0 + w * 16 + (l >> 4) * 4 + rg;
    if (row < M) {
      float dsc = dinv[row];
#pragma unroll
      for (int ct = 0; ct < NT16; ct++)
        C[(size_t)row * N + ct * 16 + (l & 15)] = f2bf(acc[ct][rg] * dsc);
    }
  }
}

// ---------------- pool (bf16 input, + bias + relu) ----------------
__global__ __launch_bounds__(256)
void k_pool(const unsigned short* __restrict__ h2, const float* __restrict__ b2,
            const int* __restrict__ batch, float* __restrict__ g) {
  int b = blockIdx.x;
  int f = threadIdx.x & 63;
  int q = threadIdx.x >> 6;
  int lo = lower_bound_i(batch, N_NODES, b);
  int hi = lower_bound_i(batch, N_NODES, b + 1);
  float bias = b2[f];
  float acc = 0.f;
  for (int i = lo + q; i < hi; i += 4)
    acc += fmaxf(__uint_as_float((uint)h2[(size_t)i * 64 + f] << 16) + bias, 0.f);
  __shared__ float red[4][64];
  red[q][f] = acc;
  __syncthreads();
  if (q == 0) g[b * 64 + f] = red[0][f] + red[1][f] + red[2][f] + red[3][f];
}

// ---------------- head ----------------
__global__ __launch_bounds__(64)
void k_final(const float* __restrict__ x0, const float* __restrict__ g,
             const float* __restrict__ Wmx, const float* __restrict__ bmx,
             const float* __restrict__ Wfc, const float* __restrict__ bfc,
             float* __restrict__ out) {
  int r = blockIdx.x;
  int c = threadIdx.x;
  __shared__ float sx[128];
  __shared__ float slog[NCLS];
  __shared__ float sred;
  float acc = bmx[c];
#pragma unroll 8
  for (int k = 0; k < 64; k++) acc = fmaf(g[r * 64 + k], Wmx[k * 64 + c], acc);
  sx[64 + c] = acc;
  sx[c] = x0[r * 64 + c];
  __syncthreads();
  float lg = 0.f;
  if (c < NCLS) {
    lg = bfc[c];
#pragma unroll 8
    for (int k = 0; k < 128; k++) lg = fmaf(sx[k], Wfc[k * NCLS + c], lg);
    slog[c] = lg;
  }
  __syncthreads();
  if (c == 0) {
    float m = -1e30f;
    for (int j = 0; j < NCLS; j++) m = fmaxf(m, slog[j]);
    float s = 0.f;
    for (int j = 0; j < NCLS; j++) s += expf(slog[j] - m);
    sred = m + logf(s);
  }
  __syncthreads();
  if (c < NCLS) out[r * NCLS + c] = lg - sred;
}

// ---------------- launch ----------------
extern "C" void kernel_launch(void* const* d_in, const int* in_sizes, int n_in,
                              void* d_out, int out_size, void* d_ws, size_t ws_size,
                              hipStream_t stream) {
  const float* x    = (const float*)d_in[0];
  const int*   edge = (const int*)d_in[1];
  const float* img  = (const float*)d_in[2];
  const int*   batch= (const int*)d_in[3];
  const float* W1   = (const float*)d_in[4];
  const float* b1   = (const float*)d_in[5];
  const float* W2   = (const float*)d_in[6];
  const float* b2   = (const float*)d_in[7];
  const float* Wm0  = (const float*)d_in[8];
  const float* bm0  = (const float*)d_in[9];
  const float* Wm1  = (const float*)d_in[10];
  const float* bm1  = (const float*)d_in[11];
  const float* Wmx  = (const float*)d_in[12];
  const float* bmx  = (const float*)d_in[13];
  const float* Wfc  = (const float*)d_in[14];
  const float* bfc  = (const float*)d_in[15];
  float* out = (float*)d_out;
  const int* srcp = edge;
  const int* dstp = edge + N_EDGES;

  char* ws = (char*)d_ws;
  size_t off = 0;
  auto alloc = [&](size_t bytes) {
    void* p = ws + off;
    off += (bytes + 255) & ~(size_t)255;
    return p;
  };
  int*   deg    = (int*)  alloc((size_t)N_NODES * 4);
  float* dinv   = (float*)alloc((size_t)N_NODES * 4);
  int*   rowptr = (int*)  alloc((size_t)(N_NODES + 1) * 4);
  int*   bsum   = (int*)  alloc((size_t)SCAN_BLOCKS * 4);
  int*   boff   = (int*)  alloc((size_t)SCAN_BLOCKS * 4);
  int*   csr    = (int*)  alloc((size_t)N_EDGES * 4);
  unsigned short* bufA = (unsigned short*)alloc((size_t)N_NODES * 128 * 2);
  size_t bufB_bytes = (size_t)KSPLIT * 65536 * 4;               // >= N_NODES*128*2
  unsigned short* bufB = (unsigned short*)alloc(bufB_bytes);
  float* tmp1   = (float*)alloc(64 * 1024 * 4);
  float* x0     = (float*)alloc(64 * 64 * 4);
  float* g      = (float*)alloc(64 * 64 * 4);
  float* partial = (float*)bufB;  // used only before agg1 writes bufB (stream-ordered)
  (void)ws_size; (void)in_sizes; (void)n_in; (void)out_size;

  // degrees -> dinv ; rowptr ; CSR (deg reused as cursor)
  hipMemsetAsync(deg, 0, (size_t)N_NODES * 4, stream);
  k_deg  <<<(N_EDGES + 255) / 256, 256, 0, stream>>>(dstp, deg);
  k_dinv <<<(N_NODES + 255) / 256, 256, 0, stream>>>(deg, dinv);
  k_scan1<<<SCAN_BLOCKS, 512, 0, stream>>>(deg, bsum);
  k_scan2<<<1, 256, 0, stream>>>(bsum, boff);
  k_scan3<<<SCAN_BLOCKS, 512, 0, stream>>>(deg, boff, rowptr);
  hipMemsetAsync(deg, 0, (size_t)N_NODES * 4, stream);
  k_csr_fill<<<(N_EDGES + 255) / 256, 256, 0, stream>>>(srcp, dstp, rowptr, deg, csr);

  // image branch (bf16 MFMA split-K, partials + reduce; no atomics)
  k_img_mfma  <<<dim3(8, KSPLIT), 256, 0, stream>>>(img, Wm0, partial);
  k_img_reduce<<<256, 256, 0, stream>>>(partial, bm0, tmp1);
  k_img_gemm2 <<<64, 256, 0, stream>>>(tmp1, Wm1, bm1, x0);

  // GCN layer 1: h1' = dinv*(x @ W1) in bf16 ; gather-agg
  k_gcn_mfma<128, false, false><<<(N_NODES + 63) / 64, 256, 0, stream>>>(
      x, W1, nullptr, dinv, bufA, N_NODES);
  k_agg_bf16<128, 8><<<(N_NODES + 15) / 16, 256, 0, stream>>>(
      bufA, dinv, rowptr, csr, bufB);

  // GCN layer 2: h2' = dinv*(relu(agg1 + b1) @ W2) in bf16 ; gather-agg
  k_gcn_mfma<64, true, true><<<(N_NODES + 63) / 64, 256, 0, stream>>>(
      bufB, W2, b1, dinv, bufA, N_NODES);
  k_agg_bf16<64, 4><<<(N_NODES + 15) / 16, 256, 0, stream>>>(
      bufA, dinv, rowptr, csr, bufB);

  // pool + head
  k_pool <<<NGR, 256, 0, stream>>>(bufB, b2, batch, g);
  k_final<<<NGR, 64, 0, stream>>>(x0, g, Wmx, bmx, Wfc, bfc, out);
}